// Round 12
// baseline (143.915 us; speedup 1.0000x reference)
//
#include <hip/hip_runtime.h>
#include <hip/hip_bf16.h>
#include <stdint.h>
#include <stddef.h>

// x[8192,512] fp32; Wq/Wk/Wv[64,512] fp32.
// out = softmax((x Wq^T)(x Wk^T)^T / 8) (x Wv^T)  -> fp32 [8192,64]
//
// R9: NS 16->32 (8 blocks/CU; K/V traffic is NS-independent, only Op partial
// traffic grows), unroll-4 KV loop. R7's fragment-order K/V layout kept.

#define SEQ    8192
#define DIN    512
#define QK_SCALE 0.18033688011112042f      // 0.125 * log2(e)

typedef __attribute__((ext_vector_type(4))) float f32x4;
typedef __attribute__((ext_vector_type(4))) short s16x4;
typedef __attribute__((ext_vector_type(8))) short s16x8;
typedef __attribute__((ext_vector_type(2))) unsigned u32x2;

__device__ __forceinline__ short bf16s(float f) {
  unsigned u = __builtin_bit_cast(unsigned, f);
  u = (u + 0x7fffu + ((u >> 16) & 1u)) >> 16;   // RNE
  return (short)u;
}

__device__ __forceinline__ float bf2f(short s) {
  unsigned u = ((unsigned)(unsigned short)s) << 16;
  return __builtin_bit_cast(float, u);
}

__device__ __forceinline__ s16x8 cvt8(f32x4 a, f32x4 b) {
  s16x8 r;
  r[0]=bf16s(a[0]); r[1]=bf16s(a[1]); r[2]=bf16s(a[2]); r[3]=bf16s(a[3]);
  r[4]=bf16s(b[0]); r[5]=bf16s(b[1]); r[6]=bf16s(b[2]); r[7]=bf16s(b[3]);
  return r;
}

// pack 2 fp32 -> 2 truncated bf16 in one v_perm_b32
__device__ __forceinline__ unsigned pk2(float hi, float lo) {
  return __builtin_amdgcn_perm(__builtin_bit_cast(unsigned, hi),
                               __builtin_bit_cast(unsigned, lo), 0x07060302u);
}

// ---------------- Kernel 1: QKV projection ----------------
// Wave-task = 512*mat + tc (tc = 16-row chunk). Outputs:
//  Q: row-major [SEQ][64] bf16, pre-scaled by QK_SCALE.
//  K: fragment order Kf[tc][ks][lane] (s16x8) via LDS transpose.
//  V: fragment order Vf[tc][db][lane] (s16x4); acc IS the fragment.
__global__ __launch_bounds__(256) void qkv_proj(
    const float* __restrict__ x,
    const float* __restrict__ Wq, const float* __restrict__ Wk,
    const float* __restrict__ Wv,
    short* __restrict__ Qo, short* __restrict__ Kf, short* __restrict__ Vf)
{
  __shared__ short lds[4][16][68];   // 68-short row pad: 2-way banks (free)
  const int wv   = threadIdx.x >> 6;
  const int lane = threadIdx.x & 63;
  const int qn   = lane & 15;
  const int g    = lane >> 4;
  const int tid  = blockIdx.x * 4 + wv;
  const int mat  = tid >> 9;          // 0=Q 1=K 2=V
  const int tc   = tid & 511;
  const int row0 = tc << 4;

  const float* W  = (mat == 0) ? Wq : (mat == 1) ? Wk : Wv;
  const float* xr = x + (size_t)(row0 + qn) * DIN + g * 8;
  const float* wr = W + (size_t)qn * DIN + g * 8;

  f32x4 acc[4] = {};

  for (int ks = 0; ks < 16; ++ks) {
    const float* xp = xr + ks * 32;
    s16x8 af = cvt8(*(const f32x4*)xp, *(const f32x4*)(xp + 4));
#pragma unroll
    for (int nt = 0; nt < 4; ++nt) {
      const float* wp = wr + (size_t)nt * 16 * DIN + ks * 32;
      s16x8 bf = cvt8(*(const f32x4*)wp, *(const f32x4*)(wp + 4));
      acc[nt] = __builtin_amdgcn_mfma_f32_16x16x32_bf16(af, bf, acc[nt], 0, 0, 0);
    }
  }

  if (mat == 0) {
#pragma unroll
    for (int nt = 0; nt < 4; ++nt)
#pragma unroll
      for (int r = 0; r < 4; ++r)
        Qo[(size_t)(row0 + 4 * g + r) * 64 + nt * 16 + qn] =
            bf16s(acc[nt][r] * QK_SCALE);
  } else if (mat == 1) {
    // acc[nt][r] = K[row0+4g+r][nt*16+qn] -> LDS [row][col] -> fragment rows
#pragma unroll
    for (int nt = 0; nt < 4; ++nt)
#pragma unroll
      for (int r = 0; r < 4; ++r)
        lds[wv][4 * g + r][nt * 16 + qn] = bf16s(acc[nt][r]);
    asm volatile("s_waitcnt lgkmcnt(0)" ::: "memory");
#pragma unroll
    for (int ks = 0; ks < 2; ++ks) {
      s16x8 f = *(const s16x8*)&lds[wv][qn][ks * 32 + g * 8];
      *(s16x8*)(Kf + ((size_t)(tc * 2 + ks) * 64 + lane) * 8) = f;
    }
  } else {
#pragma unroll
    for (int nt = 0; nt < 4; ++nt) {
      s16x4 pk;
#pragma unroll
      for (int r = 0; r < 4; ++r) pk[r] = bf16s(acc[nt][r]);
      *(s16x4*)(Vf + ((size_t)(tc * 4 + nt) * 64 + lane) * 4) = pk;
    }
  }
}

// ---------------- Kernel 2: flash attention partials ----------------
// All K/V loads are contiguous lane-indexed bursts from fragment-order ws.
// p = 2^s (constant-shift-free; normalization cancels the scale).
template<int NS>
__global__ __launch_bounds__(256) void attn_partial(
    const short* __restrict__ Q, const short* __restrict__ Kf,
    const short* __restrict__ Vf,
    short* __restrict__ Op, float* __restrict__ lp)
{
  const int lane  = threadIdx.x & 63;
  const int wv    = threadIdx.x >> 6;
  const int qn    = lane & 15;
  const int g     = lane >> 4;
  const int qblk  = blockIdx.x & 63;
  const int split = blockIdx.x >> 6;
  const int qbase = qblk * 128 + wv * 32;

  s16x8 Qf[2][2];
#pragma unroll
  for (int qt = 0; qt < 2; ++qt)
#pragma unroll
    for (int ks = 0; ks < 2; ++ks)
      Qf[qt][ks] = *(const s16x8*)(Q + (size_t)(qbase + qt * 16 + qn) * 64 + ks * 32 + g * 8);

  f32x4 acc[2][4] = {};
  float l_lane[2] = {0.f, 0.f};

  const int tcb = split * (SEQ / NS / 16);
#pragma unroll 4
  for (int c = 0; c < SEQ / NS / 32; ++c) {
    const int tc0 = tcb + c * 2;

    s16x8 Kfr[2][2];
#pragma unroll
    for (int tt = 0; tt < 2; ++tt)
#pragma unroll
      for (int ks = 0; ks < 2; ++ks)
        Kfr[tt][ks] = *(const s16x8*)(Kf + ((size_t)((tc0 + tt) * 2 + ks) * 64 + lane) * 8);

    f32x4 s[2][2];
#pragma unroll
    for (int qt = 0; qt < 2; ++qt)
#pragma unroll
      for (int tt = 0; tt < 2; ++tt) {
        f32x4 a = {};
        a = __builtin_amdgcn_mfma_f32_16x16x32_bf16(Kfr[tt][0], Qf[qt][0], a, 0, 0, 0);
        a = __builtin_amdgcn_mfma_f32_16x16x32_bf16(Kfr[tt][1], Qf[qt][1], a, 0, 0, 0);
        s[qt][tt] = a;
      }

    s16x4 Vfr[2][4];
#pragma unroll
    for (int tt = 0; tt < 2; ++tt)
#pragma unroll
      for (int db = 0; db < 4; ++db)
        Vfr[tt][db] = *(const s16x4*)(Vf + ((size_t)((tc0 + tt) * 4 + db) * 64 + lane) * 4);

#pragma unroll
    for (int qt = 0; qt < 2; ++qt) {
      float pv[2][4];
#pragma unroll
      for (int tt = 0; tt < 2; ++tt)
#pragma unroll
        for (int i = 0; i < 4; ++i) {
          pv[tt][i] = __builtin_amdgcn_exp2f(s[qt][tt][i]);
          l_lane[qt] += pv[tt][i];
        }

      s16x4 pb[2];
#pragma unroll
      for (int tt = 0; tt < 2; ++tt) {
        u32x2 w;
        w[0] = pk2(pv[tt][1], pv[tt][0]);
        w[1] = pk2(pv[tt][3], pv[tt][2]);
        pb[tt] = __builtin_bit_cast(s16x4, w);
      }

#pragma unroll
      for (int tt = 0; tt < 2; ++tt)
#pragma unroll
        for (int db = 0; db < 4; ++db)
          acc[qt][db] = __builtin_amdgcn_mfma_f32_16x16x16bf16_1k(
              Vfr[tt][db], pb[tt], acc[qt][db], 0, 0, 0);
    }
  }

#pragma unroll
  for (int qt = 0; qt < 2; ++qt) {
    const int qrow = qbase + qt * 16 + qn;
#pragma unroll
    for (int db = 0; db < 4; ++db) {
      u32x2 w;
      w[0] = (unsigned)(unsigned short)bf16s(acc[qt][db][0]) |
             ((unsigned)(unsigned short)bf16s(acc[qt][db][1]) << 16);
      w[1] = (unsigned)(unsigned short)bf16s(acc[qt][db][2]) |
             ((unsigned)(unsigned short)bf16s(acc[qt][db][3]) << 16);
      *(u32x2*)(Op + ((size_t)split * SEQ + qrow) * 64 + db * 16 + 4 * g) = w;
    }
    float ls = l_lane[qt];
    ls += __shfl_xor(ls, 16);
    ls += __shfl_xor(ls, 32);
    if (g == 0) lp[split * SEQ + qrow] = ls;
  }
}

// ---------------- Kernel 3: combine splits ----------------
template<int NS>
__global__ __launch_bounds__(256) void attn_combine(
    const short* __restrict__ Op, const float* __restrict__ lp,
    float* __restrict__ out)
{
  const int idx  = blockIdx.x * 256 + threadIdx.x;   // 8192*16
  const int qrow = idx >> 4;
  const int d0   = (idx & 15) << 2;

  float lsum = 0.f;
  f32x4 o = {};
#pragma unroll
  for (int s = 0; s < NS; ++s) {
    lsum += lp[s * SEQ + qrow];
    s16x4 ov = *(const s16x4*)(Op + ((size_t)s * SEQ + qrow) * 64 + d0);
    o[0] += bf2f(ov[0]); o[1] += bf2f(ov[1]);
    o[2] += bf2f(ov[2]); o[3] += bf2f(ov[3]);
  }
  const float inv = 1.0f / lsum;
  f32x4 r = {o[0] * inv, o[1] * inv, o[2] * inv, o[3] * inv};
  *(f32x4*)(out + (size_t)qrow * 64 + d0) = r;
}

template<int NS>
static void launch_attn(char* ws, short* Qb, short* Kf, short* Vf,
                        float* out, hipStream_t stream) {
  const size_t base = (size_t)3 << 20;
  short* Op = (short*)(ws + base);
  float* lp = (float*)(ws + base + (size_t)NS * SEQ * 64 * 2);
  attn_partial<NS><<<64 * NS, 256, 0, stream>>>(Qb, Kf, Vf, Op, lp);
  attn_combine<NS><<<512, 256, 0, stream>>>(Op, lp, out);
}

extern "C" void kernel_launch(void* const* d_in, const int* in_sizes, int n_in,
                              void* d_out, int out_size, void* d_ws, size_t ws_size,
                              hipStream_t stream) {
  const float* x  = (const float*)d_in[0];
  const float* Wq = (const float*)d_in[1];
  const float* Wk = (const float*)d_in[2];
  const float* Wv = (const float*)d_in[3];
  float* out = (float*)d_out;

  char* ws = (char*)d_ws;
  short* Qb = (short*)(ws);                         // 1 MiB
  short* Kf = (short*)(ws + (1u << 20));            // 1 MiB (fragment order)
  short* Vf = (short*)(ws + (2u << 20));            // 1 MiB (fragment order)

  qkv_proj<<<384, 256, 0, stream>>>(x, Wq, Wk, Wv, Qb, Kf, Vf);

  const size_t base = (size_t)3 << 20;
  auto need = [&](int ns) {
    return base + (size_t)ns * SEQ * 64 * 2 + (size_t)ns * SEQ * 4;
  };

  if (ws_size >= need(32))      launch_attn<32>(ws, Qb, Kf, Vf, out, stream);
  else if (ws_size >= need(16)) launch_attn<16>(ws, Qb, Kf, Vf, out, stream);
  else                          launch_attn<8> (ws, Qb, Kf, Vf, out, stream);
}